// Round 14
// baseline (694.629 us; speedup 1.0000x reference)
//
#include <hip/hip_runtime.h>
#include <stdint.h>

// OhemPairTripletLoss on MI355X (gfx950) — full-residency design:
// B-only LDS (36KB -> 4 blocks/CU), grid 1024 = whole grid resident, no
// sequential block rounds, no barrier in the wave main loop.
// loss[i,j] = relu(a_i - b_j + 2*c_ij),  c = pair1 @ pair2^T (K=128)
// out[0] = avg of top-512 distinct losses, out[1] = sum/(N*(N-1))

#define NROWS 8192
#define DDIM  128
#define MARGIN_F 0.3f
#define HALFK 512
#define SUBCAP 8192
#define SHIST_BINS 1024

typedef unsigned short u16;
typedef short bf16x8 __attribute__((ext_vector_type(8)));
typedef float f32x4 __attribute__((ext_vector_type(4)));

#define OFF_P1B  0
#define OFF_P2B  (2*1024*1024)
#define OFF_AARR (4*1024*1024)
#define OFF_BARR (OFF_AARR + 32768)
#define OFF_MISC (OFF_AARR + 65536)
#define OFF_CAND (OFF_MISC + 8192)

__device__ __forceinline__ u16 f2bf(float f) {
    unsigned int u = __float_as_uint(f);
    u = (u + 0x7FFFu + ((u >> 16) & 1u)) >> 16;
    return (u16)u;
}
__device__ __forceinline__ float bf2f(u16 u) {
    return __uint_as_float(((unsigned int)u) << 16);
}

// prep + init fused: block 0 also zeroes the misc area (hist+counters)
__global__ __launch_bounds__(256) void prep_kernel(
    const float* __restrict__ p1, const float* __restrict__ p2,
    u16* __restrict__ p1b, u16* __restrict__ p2b,
    float* __restrict__ aArr, float* __restrict__ bArr,
    int* __restrict__ misc)
{
    if (blockIdx.x == 0) {
        for (int i = threadIdx.x; i < 1232; i += 256) misc[i] = 0;
    }
    const int wid = threadIdx.x >> 6, lane = threadIdx.x & 63;
    const int row = blockIdx.x*4 + wid;
    const float2 v1 = *(const float2*)&p1[row*DDIM + lane*2];
    const float2 v2 = *(const float2*)&p2[row*DDIM + lane*2];
    p1b[row*DDIM + lane*2]     = f2bf(v1.x);
    p1b[row*DDIM + lane*2 + 1] = f2bf(v1.y);
    p2b[row*DDIM + lane*2]     = f2bf(v2.x);
    p2b[row*DDIM + lane*2 + 1] = f2bf(v2.y);
    float sq = v2.x*v2.x + v2.y*v2.y;
    float cp = v1.x*v2.x + v1.y*v2.y;
    #pragma unroll
    for (int off = 32; off > 0; off >>= 1) {
        sq += __shfl_down(sq, off);
        cp += __shfl_down(cp, off);
    }
    if (lane == 0) {
        bArr[row] = sq;
        aArr[row] = sq - 2.0f*cp + MARGIN_F;
    }
}

__global__ __launch_bounds__(256) void sample_kernel(
    const u16* __restrict__ p1b, const u16* __restrict__ p2b,
    const float* __restrict__ aArr, const float* __restrict__ bArr,
    int* __restrict__ shist)
{
    __shared__ float p1row[DDIM];
    __shared__ int h[SHIST_BINS];
    const int b = blockIdx.x;
    const int i = (b >> 3)*1024 + 512;
    const int j0 = (b & 7)*1024;
    const int tid = threadIdx.x;
    for (int k = tid; k < SHIST_BINS; k += 256) h[k] = 0;
    if (tid < DDIM) p1row[tid] = bf2f(p1b[i*DDIM + tid]);
    __syncthreads();
    const float ai = aArr[i];
    #pragma unroll
    for (int jj = 0; jj < 4; ++jj) {
        const int j = j0 + jj*256 + tid;
        const u16* prow = &p2b[j*DDIM];
        float dot = 0.f;
        for (int k = 0; k < DDIM; k += 8) {
            uint4 q = *(const uint4*)&prow[k];
            const u16* e = (const u16*)&q;
            #pragma unroll
            for (int t = 0; t < 8; ++t) dot += p1row[k + t] * bf2f(e[t]);
        }
        float v = ai - bArr[j] + 2.0f*dot;
        if (j != i && v > 0.f) {
            int bin = (int)(v * 4.0f);
            if (bin > SHIST_BINS - 1) bin = SHIST_BINS - 1;
            atomicAdd(&h[bin], 1);
        }
    }
    __syncthreads();
    for (int k = tid; k < SHIST_BINS; k += 256) if (h[k]) atomicAdd(&shist[k], h[k]);
}

__global__ __launch_bounds__(256) void pick_kernel(
    const int* __restrict__ shist, float* __restrict__ Tv)
{
    __shared__ int h[SHIST_BINS];
    __shared__ int chunk[256];
    const int tid = threadIdx.x;
    #pragma unroll
    for (int k = 0; k < 4; ++k) h[tid + k*256] = shist[tid + k*256];
    __syncthreads();
    int cs = 0;
    #pragma unroll
    for (int k = 0; k < 4; ++k) cs += h[tid*4 + k];
    chunk[tid] = cs;
    __syncthreads();
    if (tid == 0) {
        int run = 0, tc = -1;
        for (int t = 255; t >= 0; --t) {
            if (run + chunk[t] >= 8) { tc = t; break; }
            run += chunk[t];
        }
        float t0 = 0.f;
        if (tc >= 0) {
            int b = tc*4 + 3;
            for (; b >= tc*4; --b) { run += h[b]; if (run >= 8) break; }
            if (b < tc*4) b = tc*4;
            while (run > 24 && run - h[b] >= 8 && b < SHIST_BINS - 1) { run -= h[b]; b++; }
            t0 = 0.25f * (float)b;
        }
        *Tv = t0;
    }
}

// ---------------------------------------------------------------------------
// pair_gemm: grid (64 j-panels, 16 i-groups) = 1024 blocks = 4/CU, ALL
// resident. 256 thr (4 waves). B tile [128 cols][K=128] staged once in padded
// LDS (~36KB). Each wave: 128-row sub-strip, 8 iterations of 16 rows:
// 4 global A-frag loads + 32 ds_read + 32 MFMA + 32-cell epilogue.
// One barrier total (after B staging); no barrier in the main loop.
// ---------------------------------------------------------------------------
__global__ __launch_bounds__(256) void pair_gemm(
    const u16* __restrict__ p1b, const u16* __restrict__ p2b,
    const float* __restrict__ aArr, const float* __restrict__ bArr,
    const float* __restrict__ Tv,
    float* __restrict__ pS, int* __restrict__ pP,
    int* __restrict__ candCnt, float* __restrict__ cand)
{
    __shared__ u16 Bt[128][136];   // +8 pad: proven conflict-reducer
    __shared__ float sredS[4];
    __shared__ int   sredP[4];
    const int tid = threadIdx.x;
    const int bj = blockIdx.x;       // j-panel: 128 cols
    const int gi = blockIdx.y;       // i-group: 512 rows
    const int j0 = bj*128;
    const float T0 = *Tv;
    // stage B tile: 128 rows x 256B = 2048 uint4, 8 per thread
    #pragma unroll
    for (int it = 0; it < 8; ++it) {
        int c = tid + it*256;
        int r = c >> 4, cc = (c & 15) * 8;
        *(uint4*)&Bt[r][cc] = *(const uint4*)&p2b[(j0 + r)*DDIM + cc];
    }
    __syncthreads();
    const int lane = tid & 63, w = tid >> 6;
    const int r16 = lane & 15, hi = lane >> 4;
    const int row0 = gi*512 + w*128;           // wave's 128-row sub-strip
    float bv[8];
    #pragma unroll
    for (int ni = 0; ni < 8; ++ni) bv[ni] = bArr[j0 + ni*16 + r16];
    const int copy = ((bj*16 + gi)*4 + w) & 63;
    int*   myCnt  = &candCnt[copy];
    float* myCand = &cand[(size_t)copy * SUBCAP];
    float lsum = 0.f; int pcnt = 0;

    for (int t = 0; t < 8; ++t) {
        const int rr = row0 + t*16;
        bf16x8 aF[4];
        #pragma unroll
        for (int ks = 0; ks < 4; ++ks)
            aF[ks] = *(const bf16x8*)&p1b[(rr + r16)*DDIM + ks*32 + hi*8];
        float av[4];
        #pragma unroll
        for (int r = 0; r < 4; ++r) av[r] = aArr[rr + hi*4 + r];

        f32x4 acc[8];
        #pragma unroll
        for (int ni = 0; ni < 8; ++ni) acc[ni] = (f32x4){0.f, 0.f, 0.f, 0.f};
        #pragma unroll
        for (int ks = 0; ks < 4; ++ks) {
            const int kc = ks*32 + hi*8;
            bf16x8 bF[8];
            #pragma unroll
            for (int ni = 0; ni < 8; ++ni) bF[ni] = *(const bf16x8*)&Bt[ni*16 + r16][kc];
            #pragma unroll
            for (int ni = 0; ni < 8; ++ni)
                acc[ni] = __builtin_amdgcn_mfma_f32_16x16x32_bf16(aF[ks], bF[ni], acc[ni], 0, 0, 0);
        }

        const int iL = rr + hi*4;
        #pragma unroll
        for (int ni = 0; ni < 8; ++ni) {
            const bool hasDiag = rr == (j0 + ni*16);
            #pragma unroll
            for (int r = 0; r < 4; ++r) {
                const float v = av[r] - bv[ni] + 2.0f*acc[ni][r];
                lsum += fmaxf(v, 0.f);            // diagonal included; subtracted in select
                pcnt += (v > 0.f) ? 1 : 0;
                bool ok = (v >= T0);
                if (hasDiag && (hi*4 + r) == r16) ok = false;
                if (ok) {
                    int idx = atomicAdd(myCnt, 1);
                    if (idx < SUBCAP) myCand[idx] = v;
                }
            }
        }
    }

    #pragma unroll
    for (int off = 32; off > 0; off >>= 1) {
        lsum += __shfl_down(lsum, off);
        pcnt += __shfl_down(pcnt, off);
    }
    if (lane == 0) { sredS[w] = lsum; sredP[w] = pcnt; }
    __syncthreads();
    if (tid == 0) {
        atomicAdd(&pS[copy], sredS[0] + sredS[1] + sredS[2] + sredS[3]);
        atomicAdd(&pP[copy], sredP[0] + sredP[1] + sredP[2] + sredP[3]);
    }
}

__device__ __forceinline__ float block_reduce1024(float v, float* red, int tid) {
    #pragma unroll
    for (int off = 32; off > 0; off >>= 1) v += __shfl_down(v, off);
    __syncthreads();
    if ((tid & 63) == 0) red[tid >> 6] = v;
    __syncthreads();
    if (tid == 0) {
        float t = 0.f;
        #pragma unroll
        for (int w = 0; w < 16; ++w) t += red[w];
        red[0] = t;
    }
    __syncthreads();
    return red[0];
}

__global__ __launch_bounds__(1024) void select_kernel(
    const float* __restrict__ pS, const int* __restrict__ pP,
    const int* __restrict__ candCnt, const float* __restrict__ cand,
    const float* __restrict__ Tv, float* __restrict__ out)
{
    __shared__ int h1[1024];
    __shared__ int h2[1024];
    __shared__ float red[16];
    __shared__ int ints[8];
    __shared__ float fl[2];
    __shared__ float lst[4096];
    const int tid = threadIdx.x;
    for (int k = tid; k < 1024; k += 1024) { h1[k] = 0; h2[k] = 0; }
    if (tid == 0) {
        double sd = 0.0; int p = 0, c = 0;
        for (int k = 0; k < 64; ++k) {
            sd += (double)pS[k];
            p += pP[k];
            int cc = candCnt[k];
            c += (cc > SUBCAP ? SUBCAP : cc);
        }
        // analytic diagonal: every diag loss = relu(MARGIN) = 0.3, counted positive
        sd -= (double)NROWS * (double)MARGIN_F;
        if (sd < 0.0) sd = 0.0;
        p -= NROWS;
        if (p < 0) p = 0;
        ints[0] = p; ints[1] = c; ints[6] = 0;
        fl[0] = (float)sd;
    }
    __syncthreads();
    const int P = ints[0], C = ints[1];
    const float S = fl[0];
    const float all_loss = S * (1.0f / 67100672.0f);
    const float lo = *Tv;
    float avg = 0.f;

    if (P == 0) {
        avg = 0.f;
    } else if (P < HALFK) {
        avg = S / (float)P;
    } else if (C < HALFK) {
        float s = 0.f;
        for (int c = 0; c < 64; ++c) {
            int n = min(candCnt[c], SUBCAP);
            for (int k = tid; k < n; k += 1024) s += cand[(size_t)c*SUBCAP + k];
        }
        s = block_reduce1024(s, red, tid);
        avg = (C > 0) ? (s + (float)(HALFK - C)*lo) / (float)HALFK : 0.f;
    } else {
        for (int c = 0; c < 64; ++c) {
            int n = min(candCnt[c], SUBCAP);
            for (int k = tid; k < n; k += 1024) {
                float v = cand[(size_t)c*SUBCAP + k];
                int b = (int)((v - lo) * 0.25f);
                b = b < 0 ? 0 : (b > 1023 ? 1023 : b);
                atomicAdd(&h1[b], 1);
            }
        }
        __syncthreads();
        if (tid == 0) {
            int run = 0;
            for (int b = 1023; b >= 0; --b) {
                run += h1[b];
                if (run >= HALFK) { ints[2] = b; ints[3] = HALFK - (run - h1[b]); break; }
            }
        }
        __syncthreads();
        const int b1 = ints[2], needK = ints[3];
        const float lo2 = lo + (float)b1 * 4.0f;
        float s1 = 0.f;
        for (int c = 0; c < 64; ++c) {
            int n = min(candCnt[c], SUBCAP);
            for (int k = tid; k < n; k += 1024) {
                float v = cand[(size_t)c*SUBCAP + k];
                int b = (int)((v - lo) * 0.25f);
                b = b < 0 ? 0 : (b > 1023 ? 1023 : b);
                if (b > b1) s1 += v;
                else if (b == b1) {
                    int sb = (int)((v - lo2) * 256.0f);
                    sb = sb < 0 ? 0 : (sb > 1023 ? 1023 : sb);
                    atomicAdd(&h2[sb], 1);
                }
            }
        }
        s1 = block_reduce1024(s1, red, tid);
        if (tid == 0) {
            int run = 0;
            for (int b = 1023; b >= 0; --b) {
                run += h2[b];
                if (run >= needK) { ints[4] = b; ints[5] = needK - (run - h2[b]); break; }
            }
        }
        __syncthreads();
        const int b2 = ints[4], need3 = ints[5];
        float s2 = 0.f;
        for (int c = 0; c < 64; ++c) {
            int n = min(candCnt[c], SUBCAP);
            for (int k = tid; k < n; k += 1024) {
                float v = cand[(size_t)c*SUBCAP + k];
                int b = (int)((v - lo) * 0.25f);
                b = b < 0 ? 0 : (b > 1023 ? 1023 : b);
                if (b == b1) {
                    int sb = (int)((v - lo2) * 256.0f);
                    sb = sb < 0 ? 0 : (sb > 1023 ? 1023 : sb);
                    if (sb > b2) s2 += v;
                    else if (sb == b2) {
                        int idx = atomicAdd(&ints[6], 1);
                        if (idx < 4096) lst[idx] = v;
                    }
                }
            }
        }
        s2 = block_reduce1024(s2, red, tid);
        __syncthreads();
        const int m = min(ints[6], 4096);
        float s3 = 0.f;
        for (int k = tid; k < m; k += 1024) {
            float v = lst[k]; int g = 0;
            for (int j = 0; j < m; ++j) {
                float u = lst[j];
                g += (u > v) || (u == v && j < k);
            }
            if (g < need3) s3 += v;
        }
        s3 = block_reduce1024(s3, red, tid);
        avg = (s1 + s2 + s3) * (1.0f / (float)HALFK);
    }
    if (tid == 0) { out[0] = avg; out[1] = all_loss; }
}

extern "C" void kernel_launch(void* const* d_in, const int* in_sizes, int n_in,
                              void* d_out, int out_size, void* d_ws, size_t ws_size,
                              hipStream_t stream)
{
    const float* p1 = (const float*)d_in[0];
    const float* p2 = (const float*)d_in[1];
    char* ws = (char*)d_ws;
    u16*   p1b  = (u16*)(ws + OFF_P1B);
    u16*   p2b  = (u16*)(ws + OFF_P2B);
    float* aArr = (float*)(ws + OFF_AARR);
    float* bArr = (float*)(ws + OFF_BARR);
    int*   misc = (int*)(ws + OFF_MISC);
    int*   shist = misc;
    float* pS   = (float*)(misc + 1024);
    int*   pP   = misc + 1088;
    int*   cCnt = misc + 1152;
    float* Tv   = (float*)(misc + 1216);
    float* cand = (float*)(ws + OFF_CAND);
    float* out  = (float*)d_out;

    prep_kernel<<<NROWS/4, 256, 0, stream>>>(p1, p2, p1b, p2b, aArr, bArr, misc);
    sample_kernel<<<64, 256, 0, stream>>>(p1b, p2b, aArr, bArr, shist);
    pick_kernel<<<1, 256, 0, stream>>>(shist, Tv);
    dim3 grid(64, 16);
    pair_gemm<<<grid, 256, 0, stream>>>(p1b, p2b, aArr, bArr, Tv, pS, pP, cCnt, cand);
    select_kernel<<<1, 1024, 0, stream>>>(pS, pP, cCnt, cand, Tv, out);
}

// Round 16
// 375.103 us; speedup vs baseline: 1.8518x; 1.8518x over previous
//
#include <hip/hip_runtime.h>
#include <stdint.h>

// OhemPairTripletLoss on MI355X (gfx950) — r13 structure, 8-wave 128x128 GEMM
// (double TLP: 4 waves/SIMD vs r7's 2, identical LDS/coalescing patterns)
// loss[i,j] = relu(a_i - b_j + 2*c_ij),  c = pair1 @ pair2^T (K=128)
// out[0] = avg of top-512 distinct losses, out[1] = sum/(N*(N-1))

#define NROWS 8192
#define DDIM  128
#define MARGIN_F 0.3f
#define HALFK 512
#define SUBCAP 8192
#define SHIST_BINS 1024

typedef unsigned short u16;
typedef short bf16x8 __attribute__((ext_vector_type(8)));
typedef float f32x4 __attribute__((ext_vector_type(4)));

#define OFF_P1B  0
#define OFF_P2B  (2*1024*1024)
#define OFF_AARR (4*1024*1024)
#define OFF_BARR (OFF_AARR + 32768)
#define OFF_MISC (OFF_AARR + 65536)
#define OFF_CAND (OFF_MISC + 8192)

__device__ __forceinline__ u16 f2bf(float f) {
    unsigned int u = __float_as_uint(f);
    u = (u + 0x7FFFu + ((u >> 16) & 1u)) >> 16;
    return (u16)u;
}
__device__ __forceinline__ float bf2f(u16 u) {
    return __uint_as_float(((unsigned int)u) << 16);
}

// prep + init fused: block 0 zeroes misc (hist + counters)
__global__ __launch_bounds__(256) void prep_kernel(
    const float* __restrict__ p1, const float* __restrict__ p2,
    u16* __restrict__ p1b, u16* __restrict__ p2b,
    float* __restrict__ aArr, float* __restrict__ bArr,
    int* __restrict__ misc)
{
    if (blockIdx.x == 0) {
        for (int i = threadIdx.x; i < 1232; i += 256) misc[i] = 0;
    }
    const int wid = threadIdx.x >> 6, lane = threadIdx.x & 63;
    const int row = blockIdx.x*4 + wid;
    const float2 v1 = *(const float2*)&p1[row*DDIM + lane*2];
    const float2 v2 = *(const float2*)&p2[row*DDIM + lane*2];
    p1b[row*DDIM + lane*2]     = f2bf(v1.x);
    p1b[row*DDIM + lane*2 + 1] = f2bf(v1.y);
    p2b[row*DDIM + lane*2]     = f2bf(v2.x);
    p2b[row*DDIM + lane*2 + 1] = f2bf(v2.y);
    float sq = v2.x*v2.x + v2.y*v2.y;
    float cp = v1.x*v2.x + v1.y*v2.y;
    #pragma unroll
    for (int off = 32; off > 0; off >>= 1) {
        sq += __shfl_down(sq, off);
        cp += __shfl_down(cp, off);
    }
    if (lane == 0) {
        bArr[row] = sq;
        aArr[row] = sq - 2.0f*cp + MARGIN_F;
    }
}

__global__ __launch_bounds__(256) void sample_kernel(
    const u16* __restrict__ p1b, const u16* __restrict__ p2b,
    const float* __restrict__ aArr, const float* __restrict__ bArr,
    int* __restrict__ shist)
{
    __shared__ float p1row[DDIM];
    __shared__ int h[SHIST_BINS];
    const int b = blockIdx.x;
    const int i = (b >> 3)*1024 + 512;
    const int j0 = (b & 7)*1024;
    const int tid = threadIdx.x;
    for (int k = tid; k < SHIST_BINS; k += 256) h[k] = 0;
    if (tid < DDIM) p1row[tid] = bf2f(p1b[i*DDIM + tid]);
    __syncthreads();
    const float ai = aArr[i];
    #pragma unroll
    for (int jj = 0; jj < 4; ++jj) {
        const int j = j0 + jj*256 + tid;
        const u16* prow = &p2b[j*DDIM];
        float dot = 0.f;
        for (int k = 0; k < DDIM; k += 8) {
            uint4 q = *(const uint4*)&prow[k];
            const u16* e = (const u16*)&q;
            #pragma unroll
            for (int t = 0; t < 8; ++t) dot += p1row[k + t] * bf2f(e[t]);
        }
        float v = ai - bArr[j] + 2.0f*dot;
        if (j != i && v > 0.f) {
            int bin = (int)(v * 4.0f);
            if (bin > SHIST_BINS - 1) bin = SHIST_BINS - 1;
            atomicAdd(&h[bin], 1);
        }
    }
    __syncthreads();
    for (int k = tid; k < SHIST_BINS; k += 256) if (h[k]) atomicAdd(&shist[k], h[k]);
}

__global__ __launch_bounds__(256) void pick_kernel(
    const int* __restrict__ shist, float* __restrict__ Tv)
{
    __shared__ int h[SHIST_BINS];
    __shared__ int chunk[256];
    const int tid = threadIdx.x;
    #pragma unroll
    for (int k = 0; k < 4; ++k) h[tid + k*256] = shist[tid + k*256];
    __syncthreads();
    int cs = 0;
    #pragma unroll
    for (int k = 0; k < 4; ++k) cs += h[tid*4 + k];
    chunk[tid] = cs;
    __syncthreads();
    if (tid == 0) {
        int run = 0, tc = -1;
        for (int t = 255; t >= 0; --t) {
            if (run + chunk[t] >= 8) { tc = t; break; }
            run += chunk[t];
        }
        float t0 = 0.f;
        if (tc >= 0) {
            int b = tc*4 + 3;
            for (; b >= tc*4; --b) { run += h[b]; if (run >= 8) break; }
            if (b < tc*4) b = tc*4;
            while (run > 24 && run - h[b] >= 8 && b < SHIST_BINS - 1) { run -= h[b]; b++; }
            t0 = 0.25f * (float)b;
        }
        *Tv = t0;
    }
}

// ---------------------------------------------------------------------------
// pair_gemm: 128x128 tile, 512 threads = 8 waves (2x4), each wave a 64x32
// sub-tile (4x2 fragments). LDS identical to r7 (padded, 69.7KB) -> 2
// blocks/CU -> 4 waves/SIMD (2x r7's TLP). Epilogue per element = r7.
// ---------------------------------------------------------------------------
__global__ __launch_bounds__(512, 4) void pair_gemm(
    const u16* __restrict__ p1b, const u16* __restrict__ p2b,
    const float* __restrict__ aArr, const float* __restrict__ bArr,
    const float* __restrict__ Tv,
    float* __restrict__ pS, int* __restrict__ pP,
    int* __restrict__ candCnt, float* __restrict__ cand)
{
    __shared__ u16 At[128][136];   // +8 pad: proven conflict-reducer
    __shared__ u16 Bt[128][136];
    __shared__ float sredS[8];
    __shared__ int   sredP[8];
    const int tid = threadIdx.x;
    const int bi = blockIdx.y, bj = blockIdx.x;
    const int i0 = bi*128, j0 = bj*128;
    const float T0 = *Tv;
    #pragma unroll
    for (int it = 0; it < 4; ++it) {
        int c = tid + it*512;
        int r = c >> 4, cc = (c & 15) * 8;
        *(uint4*)&At[r][cc] = *(const uint4*)&p1b[(i0 + r)*DDIM + cc];
        *(uint4*)&Bt[r][cc] = *(const uint4*)&p2b[(j0 + r)*DDIM + cc];
    }
    __syncthreads();
    const int lane = tid & 63, wid = tid >> 6;
    const int r16 = lane & 15, hi = lane >> 4;
    const int wm = (wid >> 2)*64;     // 0 | 64
    const int wn = (wid & 3)*32;      // 0 | 32 | 64 | 96
    f32x4 acc[4][2];
    #pragma unroll
    for (int a = 0; a < 4; ++a)
        #pragma unroll
        for (int b = 0; b < 2; ++b) acc[a][b] = (f32x4){0.f, 0.f, 0.f, 0.f};
    #pragma unroll
    for (int ks = 0; ks < 4; ++ks) {
        const int kc = ks*32 + hi*8;
        bf16x8 aF[4], bF[2];
        #pragma unroll
        for (int mi = 0; mi < 4; ++mi) aF[mi] = *(const bf16x8*)&At[wm + mi*16 + r16][kc];
        #pragma unroll
        for (int ni = 0; ni < 2; ++ni) bF[ni] = *(const bf16x8*)&Bt[wn + ni*16 + r16][kc];
        #pragma unroll
        for (int mi = 0; mi < 4; ++mi)
            #pragma unroll
            for (int ni = 0; ni < 2; ++ni)
                acc[mi][ni] = __builtin_amdgcn_mfma_f32_16x16x32_bf16(aF[mi], bF[ni], acc[mi][ni], 0, 0, 0);
    }
    float bv[2], av[4][4];
    #pragma unroll
    for (int ni = 0; ni < 2; ++ni) bv[ni] = bArr[j0 + wn + ni*16 + r16];
    #pragma unroll
    for (int mi = 0; mi < 4; ++mi)
        #pragma unroll
        for (int r = 0; r < 4; ++r) av[mi][r] = aArr[i0 + wm + mi*16 + hi*4 + r];
    const int copy = (bi ^ bj) & 63;
    int*   myCnt  = &candCnt[copy];
    float* myCand = &cand[(size_t)copy * SUBCAP];
    float lsum = 0.f; int pcnt = 0;
    #pragma unroll
    for (int mi = 0; mi < 4; ++mi) {
        #pragma unroll
        for (int ni = 0; ni < 2; ++ni) {
            const bool hasDiag = (i0 + wm + mi*16) == (j0 + wn + ni*16);
            #pragma unroll
            for (int r = 0; r < 4; ++r) {
                const float v = av[mi][r] - bv[ni] + 2.0f*acc[mi][ni][r];
                lsum += fmaxf(v, 0.f);            // diagonal included; subtracted in select
                pcnt += (v > 0.f) ? 1 : 0;
                bool ok = (v >= T0);
                if (hasDiag && (hi*4 + r) == r16) ok = false;
                if (ok) {
                    int idx = atomicAdd(myCnt, 1);
                    if (idx < SUBCAP) myCand[idx] = v;
                }
            }
        }
    }
    #pragma unroll
    for (int off = 32; off > 0; off >>= 1) {
        lsum += __shfl_down(lsum, off);
        pcnt += __shfl_down(pcnt, off);
    }
    if (lane == 0) { sredS[wid] = lsum; sredP[wid] = pcnt; }
    __syncthreads();
    if (tid == 0) {
        float s = 0.f; int p = 0;
        #pragma unroll
        for (int w = 0; w < 8; ++w) { s += sredS[w]; p += sredP[w]; }
        atomicAdd(&pS[copy], s);
        atomicAdd(&pP[copy], p);
    }
}

__device__ __forceinline__ float block_reduce1024(float v, float* red, int tid) {
    #pragma unroll
    for (int off = 32; off > 0; off >>= 1) v += __shfl_down(v, off);
    __syncthreads();
    if ((tid & 63) == 0) red[tid >> 6] = v;
    __syncthreads();
    if (tid == 0) {
        float t = 0.f;
        #pragma unroll
        for (int w = 0; w < 16; ++w) t += red[w];
        red[0] = t;
    }
    __syncthreads();
    return red[0];
}

__global__ __launch_bounds__(1024) void select_kernel(
    const float* __restrict__ pS, const int* __restrict__ pP,
    const int* __restrict__ candCnt, const float* __restrict__ cand,
    const float* __restrict__ Tv, float* __restrict__ out)
{
    __shared__ int h1[1024];
    __shared__ int h2[1024];
    __shared__ float red[16];
    __shared__ int ints[8];
    __shared__ float fl[2];
    __shared__ float lst[4096];
    const int tid = threadIdx.x;
    for (int k = tid; k < 1024; k += 1024) { h1[k] = 0; h2[k] = 0; }
    if (tid == 0) {
        double sd = 0.0; int p = 0, c = 0;
        for (int k = 0; k < 64; ++k) {
            sd += (double)pS[k];
            p += pP[k];
            int cc = candCnt[k];
            c += (cc > SUBCAP ? SUBCAP : cc);
        }
        // analytic diagonal: every diag loss = relu(MARGIN) = 0.3, counted positive
        sd -= (double)NROWS * (double)MARGIN_F;
        if (sd < 0.0) sd = 0.0;
        p -= NROWS;
        if (p < 0) p = 0;
        ints[0] = p; ints[1] = c; ints[6] = 0;
        fl[0] = (float)sd;
    }
    __syncthreads();
    const int P = ints[0], C = ints[1];
    const float S = fl[0];
    const float all_loss = S * (1.0f / 67100672.0f);
    const float lo = *Tv;
    float avg = 0.f;

    if (P == 0) {
        avg = 0.f;
    } else if (P < HALFK) {
        avg = S / (float)P;
    } else if (C < HALFK) {
        float s = 0.f;
        for (int c = 0; c < 64; ++c) {
            int n = min(candCnt[c], SUBCAP);
            for (int k = tid; k < n; k += 1024) s += cand[(size_t)c*SUBCAP + k];
        }
        s = block_reduce1024(s, red, tid);
        avg = (C > 0) ? (s + (float)(HALFK - C)*lo) / (float)HALFK : 0.f;
    } else {
        for (int c = 0; c < 64; ++c) {
            int n = min(candCnt[c], SUBCAP);
            for (int k = tid; k < n; k += 1024) {
                float v = cand[(size_t)c*SUBCAP + k];
                int b = (int)((v - lo) * 0.25f);
                b = b < 0 ? 0 : (b > 1023 ? 1023 : b);
                atomicAdd(&h1[b], 1);
            }
        }
        __syncthreads();
        if (tid == 0) {
            int run = 0;
            for (int b = 1023; b >= 0; --b) {
                run += h1[b];
                if (run >= HALFK) { ints[2] = b; ints[3] = HALFK - (run - h1[b]); break; }
            }
        }
        __syncthreads();
        const int b1 = ints[2], needK = ints[3];
        const float lo2 = lo + (float)b1 * 4.0f;
        float s1 = 0.f;
        for (int c = 0; c < 64; ++c) {
            int n = min(candCnt[c], SUBCAP);
            for (int k = tid; k < n; k += 1024) {
                float v = cand[(size_t)c*SUBCAP + k];
                int b = (int)((v - lo) * 0.25f);
                b = b < 0 ? 0 : (b > 1023 ? 1023 : b);
                if (b > b1) s1 += v;
                else if (b == b1) {
                    int sb = (int)((v - lo2) * 256.0f);
                    sb = sb < 0 ? 0 : (sb > 1023 ? 1023 : sb);
                    atomicAdd(&h2[sb], 1);
                }
            }
        }
        s1 = block_reduce1024(s1, red, tid);
        if (tid == 0) {
            int run = 0;
            for (int b = 1023; b >= 0; --b) {
                run += h2[b];
                if (run >= needK) { ints[4] = b; ints[5] = needK - (run - h2[b]); break; }
            }
        }
        __syncthreads();
        const int b2 = ints[4], need3 = ints[5];
        float s2 = 0.f;
        for (int c = 0; c < 64; ++c) {
            int n = min(candCnt[c], SUBCAP);
            for (int k = tid; k < n; k += 1024) {
                float v = cand[(size_t)c*SUBCAP + k];
                int b = (int)((v - lo) * 0.25f);
                b = b < 0 ? 0 : (b > 1023 ? 1023 : b);
                if (b == b1) {
                    int sb = (int)((v - lo2) * 256.0f);
                    sb = sb < 0 ? 0 : (sb > 1023 ? 1023 : sb);
                    if (sb > b2) s2 += v;
                    else if (sb == b2) {
                        int idx = atomicAdd(&ints[6], 1);
                        if (idx < 4096) lst[idx] = v;
                    }
                }
            }
        }
        s2 = block_reduce1024(s2, red, tid);
        __syncthreads();
        const int m = min(ints[6], 4096);
        float s3 = 0.f;
        for (int k = tid; k < m; k += 1024) {
            float v = lst[k]; int g = 0;
            for (int j = 0; j < m; ++j) {
                float u = lst[j];
                g += (u > v) || (u == v && j < k);
            }
            if (g < need3) s3 += v;
        }
        s3 = block_reduce1024(s3, red, tid);
        avg = (s1 + s2 + s3) * (1.0f / (float)HALFK);
    }
    if (tid == 0) { out[0] = avg; out[1] = all_loss; }
}

extern "C" void kernel_launch(void* const* d_in, const int* in_sizes, int n_in,
                              void* d_out, int out_size, void* d_ws, size_t ws_size,
                              hipStream_t stream)
{
    const float* p1 = (const float*)d_in[0];
    const float* p2 = (const float*)d_in[1];
    char* ws = (char*)d_ws;
    u16*   p1b  = (u16*)(ws + OFF_P1B);
    u16*   p2b  = (u16*)(ws + OFF_P2B);
    float* aArr = (float*)(ws + OFF_AARR);
    float* bArr = (float*)(ws + OFF_BARR);
    int*   misc = (int*)(ws + OFF_MISC);
    int*   shist = misc;
    float* pS   = (float*)(misc + 1024);
    int*   pP   = misc + 1088;
    int*   cCnt = misc + 1152;
    float* Tv   = (float*)(misc + 1216);
    float* cand = (float*)(ws + OFF_CAND);
    float* out  = (float*)d_out;

    prep_kernel<<<NROWS/4, 256, 0, stream>>>(p1, p2, p1b, p2b, aArr, bArr, misc);
    sample_kernel<<<64, 256, 0, stream>>>(p1b, p2b, aArr, bArr, shist);
    pick_kernel<<<1, 256, 0, stream>>>(shist, Tv);
    dim3 grid(64, 64);
    pair_gemm<<<grid, 512, 0, stream>>>(p1b, p2b, aArr, bArr, Tv, pS, pP, cCnt, cand);
    select_kernel<<<1, 1024, 0, stream>>>(pS, pP, cCnt, cand, Tv, out);
}